// Round 22
// baseline (154.817 us; speedup 1.0000x reference)
//
#include <hip/hip_runtime.h>
#include <hip/hip_bf16.h>
#include <cstdint>
#include <cstddef>

typedef __attribute__((ext_vector_type(8))) __bf16 bf16x8;
typedef __attribute__((ext_vector_type(4))) float f32x4;
typedef __attribute__((ext_vector_type(16))) float f32x16;
typedef __attribute__((ext_vector_type(4))) unsigned short u16x4;
typedef __attribute__((ext_vector_type(4))) unsigned int u32x4;
typedef unsigned int u32;

#define NB 16
#define NC 512
#define NT 1024
#define NH 8
#define ND 64
#define NE 512

// async global->LDS, 16B per lane; lds ptr must be wave-uniform base
__device__ __forceinline__ void gld16(void* lds, const void* g) {
  __builtin_amdgcn_global_load_lds(
      (const __attribute__((address_space(1))) u32*)g,
      (__attribute__((address_space(3))) u32*)lds, 16, 0, 0);
}

__device__ __forceinline__ unsigned short f2bf(float f) {
  __bf16 h = (__bf16)f;
  return __builtin_bit_cast(unsigned short, h);
}

// hardware exp2 (v_exp_f32 computes 2^x)
__device__ __forceinline__ float ex2(float x) {
  float r; asm("v_exp_f32 %0, %1" : "=v"(r) : "v"(x)); return r;
}

// vdst.hi32 <-> vsrc.lo32 lane swap; both values updated (distinct regs!)
__device__ __forceinline__ void pl32swap(u32& a, u32& b) {
  asm("v_permlane32_swap_b32 %0, %1" : "+v"(a), "+v"(b));
}

// ---- fused weight transpose+convert for all 4 weights (coalesced both sides)
__global__ __launch_bounds__(256) void wt_convert4(
    const float* __restrict__ Wq, const float* __restrict__ Wk,
    const float* __restrict__ Wv, const float* __restrict__ Wo,
    __bf16* __restrict__ Wtq, __bf16* __restrict__ Wtk,
    __bf16* __restrict__ Wtv, __bf16* __restrict__ Wto)
{
  __shared__ float tile[32][33];
  const int w = blockIdx.y;
  const float* W = (w == 0) ? Wq : (w == 1) ? Wk : (w == 2) ? Wv : Wo;
  __bf16*     Wt = (w == 0) ? Wtq : (w == 1) ? Wtk : (w == 2) ? Wtv : Wto;
  const int bx = blockIdx.x & 15, by = blockIdx.x >> 4;
  const int r0 = by * 32, c0 = bx * 32;
  const int tx = threadIdx.x & 31, ty = threadIdx.x >> 5;
#pragma unroll
  for (int i = 0; i < 4; i++)
    tile[ty + i * 8][tx] = W[(size_t)(r0 + ty + i * 8) * 512 + c0 + tx];
  __syncthreads();
#pragma unroll
  for (int i = 0; i < 4; i++) {
    const int cc = ty + i * 8;
    Wt[(size_t)(c0 + cc) * 512 + r0 + tx] = (__bf16)tile[tx][cc];
  }
}

// ---------------- LayerNorm over C after (B,C,T)->(B,T,C) transpose ---------
__global__ __launch_bounds__(256) void ln_kernel(
    const float* __restrict__ X, const float* __restrict__ gam,
    const float* __restrict__ bet, __bf16* __restrict__ xn)
{
  __shared__ float tile[16][513];
  __shared__ float mu_s[16], rs_s[16];
  const int b  = blockIdx.x >> 6;
  const int t0 = (blockIdx.x & 63) << 4;
  const int tid = threadIdx.x;
  const int tl = tid & 15, c0 = tid >> 4;
  const float* Xb = X + (size_t)b * NC * NT + t0;
  for (int c = c0; c < NC; c += 16)
    tile[tl][c] = Xb[(size_t)c * NT + tl];
  __syncthreads();
  const int row = tid >> 4, sub = tid & 15;
  float s = 0.f, s2 = 0.f;
  for (int c = sub; c < NC; c += 16) { const float v = tile[row][c]; s += v; s2 += v * v; }
  s += __shfl_xor(s, 1);  s2 += __shfl_xor(s2, 1);
  s += __shfl_xor(s, 2);  s2 += __shfl_xor(s2, 2);
  s += __shfl_xor(s, 4);  s2 += __shfl_xor(s2, 4);
  s += __shfl_xor(s, 8);  s2 += __shfl_xor(s2, 8);
  const float mu   = s * (1.f / NC);
  const float var  = s2 * (1.f / NC) - mu * mu;
  const float rstd = rsqrtf(var + 1e-6f);
  if (sub == 0) { mu_s[row] = mu; rs_s[row] = rstd; }
  __syncthreads();
  __bf16* xo = xn + ((size_t)b * NT + t0) * NC;
  for (int i = tid; i < 16 * NC; i += 256) {
    const int r = i >> 9, c = i & (NC - 1);
    xo[(size_t)r * NC + c] = (__bf16)((tile[r][c] - mu_s[r]) * rs_s[r] * gam[c] + bet[c]);
  }
}

// ---------------- QKV GEMM: xn[16384][512] @ Wt[1536][512]^T ---------------
// BK=64, XOR-swizzled LDS (conflict-free b128 reads), 8 K-iterations
__global__ __launch_bounds__(256) void gemm_qkv(
    const __bf16* __restrict__ A, const __bf16* __restrict__ Wt,
    const float* __restrict__ bq, const float* __restrict__ bk, const float* __restrict__ bv,
    __bf16* __restrict__ qb, __bf16* __restrict__ kb, __bf16* __restrict__ vtb)
{
  __shared__ __align__(16) __bf16 lA[128 * 64];   // [128 m][64 k], swizzled
  __shared__ __align__(16) __bf16 lB[128 * 64];   // [128 n][64 k], swizzled
  __shared__ float tb[4][16][17];
  const int tid = threadIdx.x;
  const int wv = tid >> 6, lane = tid & 63;
  const int bid = blockIdx.x;
  const int mchunk = bid / 192, rem = bid % 192;
  const int xcd = rem & 7, loc = rem >> 3;           // loc 0..23
  const int mt = mchunk * 16 + xcd * 2 + (loc / 12);
  const int nt = loc % 12;
  const int m0 = mt << 7, n0 = nt << 7;
  const int fr = lane & 15, kq = lane >> 4;
  const int wr = wv >> 1, wc = wv & 1;
  const int swz = (fr & 7) << 4;

  const int so  = wv * 1024 + lane * 16;
  const int srr = so >> 7;
  const int scb = (so & 127) ^ ((srr & 7) << 4);
  const char* Asrc = (const char*)A  + (size_t)(m0 + srr) * 1024 + scb;
  const char* Bsrc = (const char*)Wt + (size_t)(n0 + srr) * 1024 + scb;

  f32x4 acc[4][4] = {};
  for (int k0 = 0; k0 < 8; k0++) {
#pragma unroll
    for (int is = 0; is < 4; is++) {
      gld16((char*)lA + is * 4096 + wv * 1024, Asrc + k0 * 128 + (size_t)is * 32768);
      gld16((char*)lB + is * 4096 + wv * 1024, Bsrc + k0 * 128 + (size_t)is * 32768);
    }
    __syncthreads();
#pragma unroll
    for (int kk = 0; kk < 2; kk++) {
      bf16x8 af[4], bfr[4];
#pragma unroll
      for (int i = 0; i < 4; i++) {
        af[i]  = *(const bf16x8*)((const char*)lA +
                   (wr * 64 + i * 16 + fr) * 128 + ((kk * 64 + kq * 16) ^ swz));
        bfr[i] = *(const bf16x8*)((const char*)lB +
                   (wc * 64 + i * 16 + fr) * 128 + ((kk * 64 + kq * 16) ^ swz));
      }
#pragma unroll
      for (int i = 0; i < 4; i++)
#pragma unroll
        for (int j = 0; j < 4; j++)
          acc[i][j] = __builtin_amdgcn_mfma_f32_16x16x32_bf16(af[i], bfr[j], acc[i][j], 0, 0, 0);
    }
    __syncthreads();
  }

  const int wsel = n0 >> 9;  // 0=q 1=k 2=v (uniform per block)
  const float* bias = (wsel == 0) ? bq : (wsel == 1) ? bk : bv;
  const float qsc = (wsel == 0) ? 0.18033688011112042f : 1.0f;  // (1/8)*log2(e)
  if (wsel < 2) {
#pragma unroll
    for (int i = 0; i < 4; i++) {
#pragma unroll
      for (int j = 0; j < 4; j++) {
        const int ng = (n0 & 511) + wc * 64 + j * 16 + fr;
        const int hh = ng >> 6, dd = ng & 63;
        const float bb = bias[ng];
#pragma unroll
        for (int r = 0; r < 4; r++) {
          const int mg = m0 + wr * 64 + i * 16 + kq * 4 + r;
          const int b = mg >> 10, t = mg & 1023;
          const __bf16 h16 = (__bf16)((acc[i][j][r] + bb) * qsc);
          if (wsel == 0) qb[(((size_t)b * NH + hh) * NT + t) * ND + dd] = h16;
          else           kb[(((size_t)b * NH + hh) * NT + t) * ND + dd] = h16;
        }
      }
    }
  } else {
    // V: per-wave LDS transpose (tb[wv] is wave-private -> no barriers)
#pragma unroll
    for (int i = 0; i < 4; i++) {
#pragma unroll
      for (int j = 0; j < 4; j++) {
#pragma unroll
        for (int r = 0; r < 4; r++) tb[wv][kq * 4 + r][fr] = acc[i][j][r];
#pragma unroll
        for (int rr = 0; rr < 4; rr++) {
          const int cloc = kq * 4 + rr;
          const int ng = (n0 & 511) + wc * 64 + j * 16 + cloc;
          const int hh = ng >> 6, dd = ng & 63;
          const int mg = m0 + wr * 64 + i * 16 + fr;
          const int b = mg >> 10, t = mg & 1023;
          vtb[(((size_t)b * NH + hh) * ND + dd) * NT + t] =
              (__bf16)(tb[wv][fr][cloc] + bias[ng]);
        }
      }
    }
  }
}

// ---------------- flash attention: QK(t+1)-lookahead pipeline ---------------
// block: 2 waves x 64 q; grid 1024; KVBLK=32; K triple-buf + V double-buf
// (20KB LDS). QK(next) issued BEFORE SM/PV(cur): next tile's MFMAs overlap
// current tile's exp2/cvt VALU. Counted vmcnt (4/2/0), no full drains.
__global__ __launch_bounds__(128) void attn_kernel(
    const __bf16* __restrict__ qb, const __bf16* __restrict__ kb,
    const __bf16* __restrict__ vtb, __bf16* __restrict__ hb)
{
  __shared__ __align__(16) __bf16 lK[3][2048];   // 3 x [32 k][64 d], swizzled
  __shared__ __align__(16) __bf16 lV[2][2048];   // 2 x packed V (128B rows)
  const int tid = threadIdx.x, wv = tid >> 6, lane = tid & 63;
  const int l31 = lane & 31, hi = lane >> 5;
  const int swz = (l31 & 7) << 4;
  const int bid = blockIdx.x;
  const int xcd = bid & 7, idx = bid >> 3;       // idx 0..127
  const int hbp = xcd * 16 + (idx >> 3);         // 0..127 = b*8+h
  const int chunk = idx & 7;
  const int b = hbp >> 3, hh = hbp & 7;
  const int q0 = chunk * 128 + wv * 64;          // wave's 64 q-rows

  const __bf16* Q = qb + ((size_t)b * NH + hh) * NT * ND;
  const char* Kc = (const char*)(kb  + ((size_t)b * NH + hh) * NT * ND);  // row 128B
  const char* Vc = (const char*)(vtb + ((size_t)b * NH + hh) * ND * NT);  // row 2048B

  // hoisted per-lane stage sources (2 gld16 per side per tile)
  const char* KsP[2];
  const char* VsP[2];
#pragma unroll
  for (int is = 0; is < 2; is++) {
    const int o  = wv * 2048 + is * 1024 + lane * 16;   // 0..4095
    const int rr = o >> 7, ob = o & 127;
    const int cb = ob ^ ((rr & 7) << 4);
    KsP[is] = Kc + (size_t)rr * 128 + cb;               // += kt*128
    const int dsub = cb >> 6, tb = cb & 63;             // packed-V inverse map
    VsP[is] = Vc + (size_t)(dsub * 32 + rr) * 2048 + tb; // += kt*2
  }

  // Q B-frags: lane: q = q0+qs*32+l31, d = ds*16 + hi*8 + j  (q pre-scaled)
  bf16x8 qf[2][4];
#pragma unroll
  for (int qs = 0; qs < 2; qs++)
#pragma unroll
    for (int ds = 0; ds < 4; ds++)
      qf[qs][ds] = *(const bf16x8*)&Q[(size_t)(q0 + qs * 32 + l31) * ND + ds * 16 + hi * 8];

  float l_run[2] = {0.f, 0.f};   // per-lane HALF sums; cross-half reduce at end
  f32x16 O[2][2] = {};
  const f32x16 zz = {};

  auto stageK = [&](int kbuf, int kt) {
#pragma unroll
    for (int is = 0; is < 2; is++)
      gld16((char*)&lK[kbuf][0] + wv * 2048 + is * 1024,
            KsP[is] + (size_t)kt * 128);
  };
  auto stageV = [&](int vbuf, int kt) {
#pragma unroll
    for (int is = 0; is < 2; is++)
      gld16((char*)&lV[vbuf][0] + wv * 2048 + is * 1024,
            VsP[is] + (size_t)kt * 2);
  };

  // QK^T for one 32-k tile: st[qs] = S^T[k=crow][q=l31] (log2 domain)
  auto qk = [&](f32x16 (&st)[2], int kbuf) {
    const char* Kb = (const char*)&lK[kbuf][0];
    __builtin_amdgcn_s_setprio(1);
#pragma unroll
    for (int ds = 0; ds < 4; ds++) {
      const bf16x8 ka = *(const bf16x8*)
          (Kb + l31 * 128 + ((ds * 32 + hi * 16) ^ swz));
      if (ds == 0) {
        st[0] = __builtin_amdgcn_mfma_f32_32x32x16_bf16(ka, qf[0][0], zz, 0, 0, 0);
        st[1] = __builtin_amdgcn_mfma_f32_32x32x16_bf16(ka, qf[1][0], zz, 0, 0, 0);
      } else {
        st[0] = __builtin_amdgcn_mfma_f32_32x32x16_bf16(ka, qf[0][ds], st[0], 0, 0, 0);
        st[1] = __builtin_amdgcn_mfma_f32_32x32x16_bf16(ka, qf[1][ds], st[1], 0, 0, 0);
      }
    }
    __builtin_amdgcn_s_setprio(0);
  };

  // SM + PV for one 32-k tile (pure-exp2 softmax; packed-V reads)
  auto smpv = [&](f32x16 (&st)[2], int vbuf) {
    const char* Vb = (const char*)&lV[vbuf][0];
#pragma unroll
    for (int qs = 0; qs < 2; qs++) {
      float rs = 0.f;
      u32 pk[4][2];
#pragma unroll
      for (int g = 0; g < 4; g++) {
        const float p0 = ex2(st[qs][4 * g + 0]);
        const float p1 = ex2(st[qs][4 * g + 1]);
        const float p2 = ex2(st[qs][4 * g + 2]);
        const float p3 = ex2(st[qs][4 * g + 3]);
        rs += (p0 + p1) + (p2 + p3);
        asm("v_cvt_pk_bf16_f32 %0, %1, %2" : "=v"(pk[g][0]) : "v"(p0), "v"(p1));
        asm("v_cvt_pk_bf16_f32 %0, %1, %2" : "=v"(pk[g][1]) : "v"(p2), "v"(p3));
      }
      l_run[qs] += rs;
      __builtin_amdgcn_s_setprio(1);
#pragma unroll
      for (int s = 0; s < 2; s++) {
        u32 a0 = pk[2 * s][0], b0 = pk[2 * s + 1][0];
        u32 a1 = pk[2 * s][1], b1 = pk[2 * s + 1][1];
        pl32swap(a0, b0);
        pl32swap(a1, b1);
        u32x4 w;
        w[0] = a0; w[1] = a1; w[2] = b0; w[3] = b1;
        const bf16x8 pfrag = __builtin_bit_cast(bf16x8, w);
#pragma unroll
        for (int dsub = 0; dsub < 2; dsub++) {
          const bf16x8 vf = *(const bf16x8*)
              (Vb + l31 * 128 + ((dsub * 64 + s * 32 + hi * 16) ^ swz));
          O[qs][dsub] = __builtin_amdgcn_mfma_f32_32x32x16_bf16(vf, pfrag, O[qs][dsub], 0, 0, 0);
        }
      }
      __builtin_amdgcn_s_setprio(0);
    }
  };

  f32x16 stA[2], stB[2];

  // prologue: K0 | [K1,V0] | [K2,V1]  (pairs match steady-state batches)
  stageK(0, 0);
  stageK(1, 32); stageV(0, 0);
  stageK(2, 64); stageV(1, 32);
  asm volatile("s_waitcnt vmcnt(8)" ::: "memory");   // K0 done (own wave)
  __builtin_amdgcn_s_barrier();                      // all waves' K0 done
  __builtin_amdgcn_sched_barrier(0);
  qk(stA, 0);                                        // QK(0)

  int b0 = 0, b1 = 1, b2 = 2;  // K buf of tiles te, te+1, te+2
#pragma unroll 1
  for (int it = 0; it < 16; it++) {
    const int te = 2 * it;
    // ---- even phase: tile te (V buf 0); lookahead QK(te+1)
    if (te < 30) asm volatile("s_waitcnt vmcnt(4)" ::: "memory");
    else         asm volatile("s_waitcnt vmcnt(2)" ::: "memory");
    __builtin_amdgcn_s_barrier();
    __builtin_amdgcn_sched_barrier(0);
    qk(stB, b1);
    smpv(stA, 0);
    __builtin_amdgcn_s_barrier();
    __builtin_amdgcn_sched_barrier(0);
    if (te <= 28) stageK(b0, (te + 3) * 32);
    if (te <= 29) stageV(0, (te + 2) * 32);
    // ---- odd phase: tile to = te+1 (V buf 1); lookahead QK(to+1)
    const int to = te + 1;
    if (to <= 29) asm volatile("s_waitcnt vmcnt(4)" ::: "memory");
    else          asm volatile("s_waitcnt vmcnt(0)" ::: "memory");
    __builtin_amdgcn_s_barrier();
    __builtin_amdgcn_sched_barrier(0);
    if (to < 31) qk(stA, b2);
    smpv(stB, 1);
    __builtin_amdgcn_s_barrier();
    __builtin_amdgcn_sched_barrier(0);
    if (to <= 28) stageK(b1, (to + 3) * 32);
    if (to <= 29) stageV(1, (to + 2) * 32);
    // rotate K buffers: tiles advance by 2 per iteration
    const int n0_ = b2, n1_ = b0, n2_ = b1;
    b0 = n0_; b1 = n1_; b2 = n2_;
  }

  // ---- epilogue: lane holds O^T col q = l31; d = 32dsub + 8g + 4hi + rr
#pragma unroll
  for (int qs = 0; qs < 2; qs++) {
    const float lt = l_run[qs] + __shfl_xor(l_run[qs], 32);
    const float linv = 1.f / lt;
    const int t = q0 + qs * 32 + l31;
    __bf16* hrow = hb + ((size_t)b * NT + t) * NE + hh * ND;
#pragma unroll
    for (int dsub = 0; dsub < 2; dsub++)
#pragma unroll
      for (int g = 0; g < 4; g++) {
        u16x4 ov;
#pragma unroll
        for (int rr = 0; rr < 4; rr++) ov[rr] = f2bf(O[qs][dsub][4 * g + rr] * linv);
        *(u16x4*)&hrow[dsub * 32 + g * 8 + hi * 4] = ov;
      }
  }
}

// ---------------- out proj + bias + residual + transpose store -------------
// BK=64, XOR-swizzled LDS, 8 K-iterations; XCD-swizzled grid 512
__global__ __launch_bounds__(256) void gemm_out(
    const __bf16* __restrict__ A, const __bf16* __restrict__ Wt,
    const float* __restrict__ bo, const float* __restrict__ X,
    float* __restrict__ out)
{
  __shared__ __align__(16) __bf16 lA[128 * 64];
  __shared__ __align__(16) __bf16 lB[128 * 64];
  __shared__ float tb[4][16][17];
  const int tid = threadIdx.x, wv = tid >> 6, lane = tid & 63;
  const int bid = blockIdx.x;
  const int mt = ((bid >> 5) << 3) + (bid & 7);
  const int nt = (bid & 31) >> 3;
  const int m0 = mt << 7, n0 = nt << 7;
  const int fr = lane & 15, kq = lane >> 4;
  const int wr = wv >> 1, wc = wv & 1;
  const int swz = (fr & 7) << 4;

  const int so  = wv * 1024 + lane * 16;
  const int srr = so >> 7;
  const int scb = (so & 127) ^ ((srr & 7) << 4);
  const char* Asrc = (const char*)A  + (size_t)(m0 + srr) * 1024 + scb;
  const char* Bsrc = (const char*)Wt + (size_t)(n0 + srr) * 1024 + scb;

  f32x4 acc[4][4] = {};
  for (int k0 = 0; k0 < 8; k0++) {
#pragma unroll
    for (int is = 0; is < 4; is++) {
      gld16((char*)lA + is * 4096 + wv * 1024, Asrc + k0 * 128 + (size_t)is * 32768);
      gld16((char*)lB + is * 4096 + wv * 1024, Bsrc + k0 * 128 + (size_t)is * 32768);
    }
    __syncthreads();
#pragma unroll
    for (int kk = 0; kk < 2; kk++) {
      bf16x8 af[4], bfr[4];
#pragma unroll
      for (int i = 0; i < 4; i++) {
        af[i]  = *(const bf16x8*)((const char*)lA +
                   (wr * 64 + i * 16 + fr) * 128 + ((kk * 64 + kq * 16) ^ swz));
        bfr[i] = *(const bf16x8*)((const char*)lB +
                   (wc * 64 + i * 16 + fr) * 128 + ((kk * 64 + kq * 16) ^ swz));
      }
#pragma unroll
      for (int i = 0; i < 4; i++)
#pragma unroll
        for (int j = 0; j < 4; j++)
          acc[i][j] = __builtin_amdgcn_mfma_f32_16x16x32_bf16(af[i], bfr[j], acc[i][j], 0, 0, 0);
    }
    __syncthreads();
  }

  // fully-unrolled per-wave LDS transpose epilogue (no barriers, acc static)
#pragma unroll
  for (int i = 0; i < 4; i++) {
#pragma unroll
    for (int j = 0; j < 4; j++) {
#pragma unroll
      for (int r = 0; r < 4; r++) tb[wv][kq * 4 + r][fr] = acc[i][j][r];
#pragma unroll
      for (int rr = 0; rr < 4; rr++) {
        const int cloc = kq * 4 + rr;
        const int mg = m0 + wr * 64 + i * 16 + fr;
        const int b = mg >> 10, t = mg & 1023;
        const int c = n0 + wc * 64 + j * 16 + cloc;
        out[((size_t)b * NC + c) * NT + t] =
            tb[wv][fr][cloc] + bo[c] + X[((size_t)b * NC + c) * NT + t];
      }
    }
  }
}

// ---------------------------------------------------------------------------
extern "C" void kernel_launch(void* const* d_in, const int* in_sizes, int n_in,
                              void* d_out, int out_size, void* d_ws, size_t ws_size,
                              hipStream_t stream) {
  const float* X   = (const float*)d_in[0];
  const float* lng = (const float*)d_in[1];
  const float* lnb = (const float*)d_in[2];
  const float* Wq  = (const float*)d_in[3];
  const float* bq  = (const float*)d_in[4];
  const float* Wk  = (const float*)d_in[5];
  const float* bk  = (const float*)d_in[6];
  const float* Wv  = (const float*)d_in[7];
  const float* bv  = (const float*)d_in[8];
  const float* Wo  = (const float*)d_in[9];
  const float* bo  = (const float*)d_in[10];
  float* out = (float*)d_out;

  __bf16* wsb   = (__bf16*)d_ws;
  __bf16* Wtqkv = wsb;                 // [1536][512]
  __bf16* Wot   = wsb + 786432;        // [512][512]
  __bf16* xn    = wsb + 1048576;       // [16384][512]
  __bf16* qbuf  = wsb + 9437184;       // [B][H][T][D] (pre-scaled by log2e/8)
  __bf16* kbuf  = wsb + 17825792;      // [B][H][T][D]
  __bf16* vtbuf = wsb + 26214400;      // [B][H][D][T]
  __bf16* hbuf  = wsb + 34603008;      // [16384][512]

  wt_convert4<<<dim3(256, 4), 256, 0, stream>>>(
      Wq, Wk, Wv, Wo, Wtqkv, Wtqkv + 262144, Wtqkv + 524288, Wot);
  ln_kernel<<<NB * (NT / 16), 256, 0, stream>>>(X, lng, lnb, xn);
  gemm_qkv<<<128 * 12, 256, 0, stream>>>(xn, Wtqkv, bq, bk, bv, qbuf, kbuf, vtbuf);
  attn_kernel<<<1024, 128, 0, stream>>>(qbuf, kbuf, vtbuf, hbuf);
  gemm_out<<<128 * 4, 256, 0, stream>>>(hbuf, Wot, bo, X, out);
}

// Round 23
// 131.672 us; speedup vs baseline: 1.1758x; 1.1758x over previous
//
#include <hip/hip_runtime.h>
#include <hip/hip_bf16.h>
#include <cstdint>
#include <cstddef>

typedef __attribute__((ext_vector_type(8))) __bf16 bf16x8;
typedef __attribute__((ext_vector_type(4))) float f32x4;
typedef __attribute__((ext_vector_type(16))) float f32x16;
typedef __attribute__((ext_vector_type(4))) unsigned short u16x4;
typedef __attribute__((ext_vector_type(4))) unsigned int u32x4;
typedef unsigned int u32;

#define NB 16
#define NC 512
#define NT 1024
#define NH 8
#define ND 64
#define NE 512

// async global->LDS, 16B per lane; lds ptr must be wave-uniform base
__device__ __forceinline__ void gld16(void* lds, const void* g) {
  __builtin_amdgcn_global_load_lds(
      (const __attribute__((address_space(1))) u32*)g,
      (__attribute__((address_space(3))) u32*)lds, 16, 0, 0);
}

__device__ __forceinline__ unsigned short f2bf(float f) {
  __bf16 h = (__bf16)f;
  return __builtin_bit_cast(unsigned short, h);
}

// hardware exp2 (v_exp_f32 computes 2^x)
__device__ __forceinline__ float ex2(float x) {
  float r; asm("v_exp_f32 %0, %1" : "=v"(r) : "v"(x)); return r;
}

// vdst.hi32 <-> vsrc.lo32 lane swap; both values updated (distinct regs!)
__device__ __forceinline__ void pl32swap(u32& a, u32& b) {
  asm("v_permlane32_swap_b32 %0, %1" : "+v"(a), "+v"(b));
}

// ---- fused weight transpose+convert for all 4 weights (coalesced both sides)
__global__ __launch_bounds__(256) void wt_convert4(
    const float* __restrict__ Wq, const float* __restrict__ Wk,
    const float* __restrict__ Wv, const float* __restrict__ Wo,
    __bf16* __restrict__ Wtq, __bf16* __restrict__ Wtk,
    __bf16* __restrict__ Wtv, __bf16* __restrict__ Wto)
{
  __shared__ float tile[32][33];
  const int w = blockIdx.y;
  const float* W = (w == 0) ? Wq : (w == 1) ? Wk : (w == 2) ? Wv : Wo;
  __bf16*     Wt = (w == 0) ? Wtq : (w == 1) ? Wtk : (w == 2) ? Wtv : Wto;
  const int bx = blockIdx.x & 15, by = blockIdx.x >> 4;
  const int r0 = by * 32, c0 = bx * 32;
  const int tx = threadIdx.x & 31, ty = threadIdx.x >> 5;
#pragma unroll
  for (int i = 0; i < 4; i++)
    tile[ty + i * 8][tx] = W[(size_t)(r0 + ty + i * 8) * 512 + c0 + tx];
  __syncthreads();
#pragma unroll
  for (int i = 0; i < 4; i++) {
    const int cc = ty + i * 8;
    Wt[(size_t)(c0 + cc) * 512 + r0 + tx] = (__bf16)tile[tx][cc];
  }
}

// ---------------- LayerNorm over C after (B,C,T)->(B,T,C) transpose ---------
__global__ __launch_bounds__(256) void ln_kernel(
    const float* __restrict__ X, const float* __restrict__ gam,
    const float* __restrict__ bet, __bf16* __restrict__ xn)
{
  __shared__ float tile[16][513];
  __shared__ float mu_s[16], rs_s[16];
  const int b  = blockIdx.x >> 6;
  const int t0 = (blockIdx.x & 63) << 4;
  const int tid = threadIdx.x;
  const int tl = tid & 15, c0 = tid >> 4;
  const float* Xb = X + (size_t)b * NC * NT + t0;
  for (int c = c0; c < NC; c += 16)
    tile[tl][c] = Xb[(size_t)c * NT + tl];
  __syncthreads();
  const int row = tid >> 4, sub = tid & 15;
  float s = 0.f, s2 = 0.f;
  for (int c = sub; c < NC; c += 16) { const float v = tile[row][c]; s += v; s2 += v * v; }
  s += __shfl_xor(s, 1);  s2 += __shfl_xor(s2, 1);
  s += __shfl_xor(s, 2);  s2 += __shfl_xor(s2, 2);
  s += __shfl_xor(s, 4);  s2 += __shfl_xor(s2, 4);
  s += __shfl_xor(s, 8);  s2 += __shfl_xor(s2, 8);
  const float mu   = s * (1.f / NC);
  const float var  = s2 * (1.f / NC) - mu * mu;
  const float rstd = rsqrtf(var + 1e-6f);
  if (sub == 0) { mu_s[row] = mu; rs_s[row] = rstd; }
  __syncthreads();
  __bf16* xo = xn + ((size_t)b * NT + t0) * NC;
  for (int i = tid; i < 16 * NC; i += 256) {
    const int r = i >> 9, c = i & (NC - 1);
    xo[(size_t)r * NC + c] = (__bf16)((tile[r][c] - mu_s[r]) * rs_s[r] * gam[c] + bet[c]);
  }
}

// ---------------- QKV GEMM: xn[16384][512] @ Wt[1536][512]^T ---------------
// BK=64, XOR-swizzled LDS (conflict-free b128 reads), 8 K-iterations
__global__ __launch_bounds__(256) void gemm_qkv(
    const __bf16* __restrict__ A, const __bf16* __restrict__ Wt,
    const float* __restrict__ bq, const float* __restrict__ bk, const float* __restrict__ bv,
    __bf16* __restrict__ qb, __bf16* __restrict__ kb, __bf16* __restrict__ vtb)
{
  __shared__ __align__(16) __bf16 lA[128 * 64];   // [128 m][64 k], swizzled
  __shared__ __align__(16) __bf16 lB[128 * 64];   // [128 n][64 k], swizzled
  __shared__ float tb[4][16][17];
  const int tid = threadIdx.x;
  const int wv = tid >> 6, lane = tid & 63;
  const int bid = blockIdx.x;
  const int mchunk = bid / 192, rem = bid % 192;
  const int xcd = rem & 7, loc = rem >> 3;           // loc 0..23
  const int mt = mchunk * 16 + xcd * 2 + (loc / 12);
  const int nt = loc % 12;
  const int m0 = mt << 7, n0 = nt << 7;
  const int fr = lane & 15, kq = lane >> 4;
  const int wr = wv >> 1, wc = wv & 1;
  const int swz = (fr & 7) << 4;

  const int so  = wv * 1024 + lane * 16;
  const int srr = so >> 7;
  const int scb = (so & 127) ^ ((srr & 7) << 4);
  const char* Asrc = (const char*)A  + (size_t)(m0 + srr) * 1024 + scb;
  const char* Bsrc = (const char*)Wt + (size_t)(n0 + srr) * 1024 + scb;

  f32x4 acc[4][4] = {};
  for (int k0 = 0; k0 < 8; k0++) {
#pragma unroll
    for (int is = 0; is < 4; is++) {
      gld16((char*)lA + is * 4096 + wv * 1024, Asrc + k0 * 128 + (size_t)is * 32768);
      gld16((char*)lB + is * 4096 + wv * 1024, Bsrc + k0 * 128 + (size_t)is * 32768);
    }
    __syncthreads();
#pragma unroll
    for (int kk = 0; kk < 2; kk++) {
      bf16x8 af[4], bfr[4];
#pragma unroll
      for (int i = 0; i < 4; i++) {
        af[i]  = *(const bf16x8*)((const char*)lA +
                   (wr * 64 + i * 16 + fr) * 128 + ((kk * 64 + kq * 16) ^ swz));
        bfr[i] = *(const bf16x8*)((const char*)lB +
                   (wc * 64 + i * 16 + fr) * 128 + ((kk * 64 + kq * 16) ^ swz));
      }
#pragma unroll
      for (int i = 0; i < 4; i++)
#pragma unroll
        for (int j = 0; j < 4; j++)
          acc[i][j] = __builtin_amdgcn_mfma_f32_16x16x32_bf16(af[i], bfr[j], acc[i][j], 0, 0, 0);
    }
    __syncthreads();
  }

  const int wsel = n0 >> 9;  // 0=q 1=k 2=v (uniform per block)
  const float* bias = (wsel == 0) ? bq : (wsel == 1) ? bk : bv;
  const float qsc = (wsel == 0) ? 0.18033688011112042f : 1.0f;  // (1/8)*log2(e)
  if (wsel < 2) {
#pragma unroll
    for (int i = 0; i < 4; i++) {
#pragma unroll
      for (int j = 0; j < 4; j++) {
        const int ng = (n0 & 511) + wc * 64 + j * 16 + fr;
        const int hh = ng >> 6, dd = ng & 63;
        const float bb = bias[ng];
#pragma unroll
        for (int r = 0; r < 4; r++) {
          const int mg = m0 + wr * 64 + i * 16 + kq * 4 + r;
          const int b = mg >> 10, t = mg & 1023;
          const __bf16 h16 = (__bf16)((acc[i][j][r] + bb) * qsc);
          if (wsel == 0) qb[(((size_t)b * NH + hh) * NT + t) * ND + dd] = h16;
          else           kb[(((size_t)b * NH + hh) * NT + t) * ND + dd] = h16;
        }
      }
    }
  } else {
    // V: per-wave LDS transpose (tb[wv] is wave-private -> no barriers)
#pragma unroll
    for (int i = 0; i < 4; i++) {
#pragma unroll
      for (int j = 0; j < 4; j++) {
#pragma unroll
        for (int r = 0; r < 4; r++) tb[wv][kq * 4 + r][fr] = acc[i][j][r];
#pragma unroll
        for (int rr = 0; rr < 4; rr++) {
          const int cloc = kq * 4 + rr;
          const int ng = (n0 & 511) + wc * 64 + j * 16 + cloc;
          const int hh = ng >> 6, dd = ng & 63;
          const int mg = m0 + wr * 64 + i * 16 + fr;
          const int b = mg >> 10, t = mg & 1023;
          vtb[(((size_t)b * NH + hh) * ND + dd) * NT + t] =
              (__bf16)(tb[wv][fr][cloc] + bias[ng]);
        }
      }
    }
  }
}

// ---------------- flash attention: 32x32 MFMA, pure-exp2 softmax ------------
// r19 known-best: counted-vmcnt pipeline, both-softmaxes-first scheduling,
// deferred l-reduction, hoisted stage addressing
__global__ __launch_bounds__(128, 2) void attn_kernel(
    const __bf16* __restrict__ qb, const __bf16* __restrict__ kb,
    const __bf16* __restrict__ vtb, __bf16* __restrict__ hb)
{
  __shared__ __align__(16) __bf16 lK[2][4096];   // [64 k][64 d], swizzled
  __shared__ __align__(16) __bf16 lV[2][4096];   // [64 d][64 t], swizzled
  const int tid = threadIdx.x, wv = tid >> 6, lane = tid & 63;
  const int l31 = lane & 31, hi = lane >> 5;
  const int swz = (l31 & 7) << 4;
  const int bid = blockIdx.x;
  const int xcd = bid & 7, idx = bid >> 3;       // idx 0..127
  const int hbp = xcd * 16 + (idx >> 3);         // 0..127 = b*8+h
  const int chunk = idx & 7;
  const int b = hbp >> 3, hh = hbp & 7;
  const int q0 = chunk * 128 + wv * 64;          // wave's 64 q-rows

  const __bf16* Q = qb + ((size_t)b * NH + hh) * NT * ND;
  const char* Kc = (const char*)(kb  + ((size_t)b * NH + hh) * NT * ND);  // row 128B
  const char* Vc = (const char*)(vtb + ((size_t)b * NH + hh) * ND * NT);  // row 2048B

  const int so  = wv * 1024 + lane * 16;
  const int srr = so >> 7;
  const int scb = (so & 127) ^ ((srr & 7) << 4);
  const char* Ksrc0 = Kc + (size_t)srr * 128 + scb;
  const char* Vsrc0 = Vc + (size_t)srr * 2048 + scb;

  bf16x8 qf[2][4];
#pragma unroll
  for (int qs = 0; qs < 2; qs++)
#pragma unroll
    for (int ds = 0; ds < 4; ds++)
      qf[qs][ds] = *(const bf16x8*)&Q[(size_t)(q0 + qs * 32 + l31) * ND + ds * 16 + hi * 8];

  float l_run[2] = {0.f, 0.f};   // per-lane HALF sums; cross-half reduce at end
  f32x16 O[2][2] = {};
  const f32x16 zz = {};

  auto stage = [&](int nb, int kt64) {
#pragma unroll
    for (int is = 0; is < 4; is++) {
      gld16((char*)&lK[nb][0] + is * 2048 + wv * 1024,
            Ksrc0 + (size_t)kt64 * 128 + is * 2048);
      gld16((char*)&lV[nb][0] + is * 2048 + wv * 1024,
            Vsrc0 + (size_t)kt64 * 2 + is * 32768);
    }
  };

  stage(0, 0);
  stage(1, 64);

#pragma unroll 1
  for (int ti = 0; ti < 16; ti++) {
    const int cur = ti & 1;
    if (ti < 15) asm volatile("s_waitcnt vmcnt(8)" ::: "memory");
    else         asm volatile("s_waitcnt vmcnt(0)" ::: "memory");
    __builtin_amdgcn_s_barrier();
    __builtin_amdgcn_sched_barrier(0);
    const char* Kb = (const char*)&lK[cur][0];
    const char* Vb = (const char*)&lV[cur][0];

    // ---- QK^T: st[qs][ksub] = S^T[k = 32ksub+crow][q = l31] (log2 domain)
    f32x16 st[2][2];
    __builtin_amdgcn_s_setprio(1);
#pragma unroll
    for (int ks = 0; ks < 2; ks++) {
#pragma unroll
      for (int ds = 0; ds < 4; ds++) {
        const int row = ks * 32 + l31;
        const bf16x8 ka = *(const bf16x8*)
            (Kb + row * 128 + ((ds * 32 + hi * 16) ^ swz));
        if (ds == 0) {
          st[0][ks] = __builtin_amdgcn_mfma_f32_32x32x16_bf16(ka, qf[0][0], zz, 0, 0, 0);
          st[1][ks] = __builtin_amdgcn_mfma_f32_32x32x16_bf16(ka, qf[1][0], zz, 0, 0, 0);
        } else {
          st[0][ks] = __builtin_amdgcn_mfma_f32_32x32x16_bf16(ka, qf[0][ds], st[0][ks], 0, 0, 0);
          st[1][ks] = __builtin_amdgcn_mfma_f32_32x32x16_bf16(ka, qf[1][ds], st[1][ks], 0, 0, 0);
        }
      }
    }
    __builtin_amdgcn_s_setprio(0);

    // ---- both softmaxes first (pure exp2; base cancels in l-div)
    u32 pk[2][2][4][2];
#pragma unroll
    for (int qs = 0; qs < 2; qs++) {
      float rs = 0.f;
#pragma unroll
      for (int ks = 0; ks < 2; ks++)
#pragma unroll
        for (int g = 0; g < 4; g++) {
          const float p0 = ex2(st[qs][ks][4 * g + 0]);
          const float p1 = ex2(st[qs][ks][4 * g + 1]);
          const float p2 = ex2(st[qs][ks][4 * g + 2]);
          const float p3 = ex2(st[qs][ks][4 * g + 3]);
          rs += (p0 + p1) + (p2 + p3);
          asm("v_cvt_pk_bf16_f32 %0, %1, %2" : "=v"(pk[qs][ks][g][0]) : "v"(p0), "v"(p1));
          asm("v_cvt_pk_bf16_f32 %0, %1, %2" : "=v"(pk[qs][ks][g][1]) : "v"(p2), "v"(p3));
        }
      l_run[qs] += rs;
    }

    // ---- both PV clusters: 4 independent accumulation chains (qs x dsub)
    __builtin_amdgcn_s_setprio(1);
#pragma unroll
    for (int qs = 0; qs < 2; qs++) {
#pragma unroll
      for (int s = 0; s < 4; s++) {
        const int t = s >> 1, m = s & 1;
        u32 a0 = pk[qs][t][2 * m][0], b0 = pk[qs][t][2 * m + 1][0];
        u32 a1 = pk[qs][t][2 * m][1], b1 = pk[qs][t][2 * m + 1][1];
        pl32swap(a0, b0);
        pl32swap(a1, b1);
        u32x4 w;
        w[0] = a0; w[1] = a1; w[2] = b0; w[3] = b1;
        const bf16x8 pfrag = __builtin_bit_cast(bf16x8, w);
#pragma unroll
        for (int dsub = 0; dsub < 2; dsub++) {
          const int row = dsub * 32 + l31;
          const bf16x8 vf = *(const bf16x8*)
              (Vb + row * 128 + ((s * 32 + hi * 16) ^ swz));
          O[qs][dsub] = __builtin_amdgcn_mfma_f32_32x32x16_bf16(vf, pfrag, O[qs][dsub], 0, 0, 0);
        }
      }
    }
    __builtin_amdgcn_s_setprio(0);

    __builtin_amdgcn_s_barrier();
    __builtin_amdgcn_sched_barrier(0);
    if (ti + 2 < 16) stage(cur, (ti + 2) * 64);
  }

#pragma unroll
  for (int qs = 0; qs < 2; qs++) {
    const float lt = l_run[qs] + __shfl_xor(l_run[qs], 32);
    const float linv = 1.f / lt;
    const int t = q0 + qs * 32 + l31;
    __bf16* hrow = hb + ((size_t)b * NT + t) * NE + hh * ND;
#pragma unroll
    for (int dsub = 0; dsub < 2; dsub++)
#pragma unroll
      for (int g = 0; g < 4; g++) {
        u16x4 ov;
#pragma unroll
        for (int rr = 0; rr < 4; rr++) ov[rr] = f2bf(O[qs][dsub][4 * g + rr] * linv);
        *(u16x4*)&hrow[dsub * 32 + g * 8 + hi * 4] = ov;
      }
  }
}

// ---------------- out proj + bias + residual + transpose store -------------
// BK=64, XOR-swizzled LDS, 8 K-iterations; XCD-swizzled grid 512
__global__ __launch_bounds__(256) void gemm_out(
    const __bf16* __restrict__ A, const __bf16* __restrict__ Wt,
    const float* __restrict__ bo, const float* __restrict__ X,
    float* __restrict__ out)
{
  __shared__ __align__(16) __bf16 lA[128 * 64];
  __shared__ __align__(16) __bf16 lB[128 * 64];
  __shared__ float tb[4][16][17];
  const int tid = threadIdx.x, wv = tid >> 6, lane = tid & 63;
  const int bid = blockIdx.x;
  const int mt = ((bid >> 5) << 3) + (bid & 7);
  const int nt = (bid & 31) >> 3;
  const int m0 = mt << 7, n0 = nt << 7;
  const int fr = lane & 15, kq = lane >> 4;
  const int wr = wv >> 1, wc = wv & 1;
  const int swz = (fr & 7) << 4;

  const int so  = wv * 1024 + lane * 16;
  const int srr = so >> 7;
  const int scb = (so & 127) ^ ((srr & 7) << 4);
  const char* Asrc = (const char*)A  + (size_t)(m0 + srr) * 1024 + scb;
  const char* Bsrc = (const char*)Wt + (size_t)(n0 + srr) * 1024 + scb;

  f32x4 acc[4][4] = {};
  for (int k0 = 0; k0 < 8; k0++) {
#pragma unroll
    for (int is = 0; is < 4; is++) {
      gld16((char*)lA + is * 4096 + wv * 1024, Asrc + k0 * 128 + (size_t)is * 32768);
      gld16((char*)lB + is * 4096 + wv * 1024, Bsrc + k0 * 128 + (size_t)is * 32768);
    }
    __syncthreads();
#pragma unroll
    for (int kk = 0; kk < 2; kk++) {
      bf16x8 af[4], bfr[4];
#pragma unroll
      for (int i = 0; i < 4; i++) {
        af[i]  = *(const bf16x8*)((const char*)lA +
                   (wr * 64 + i * 16 + fr) * 128 + ((kk * 64 + kq * 16) ^ swz));
        bfr[i] = *(const bf16x8*)((const char*)lB +
                   (wc * 64 + i * 16 + fr) * 128 + ((kk * 64 + kq * 16) ^ swz));
      }
#pragma unroll
      for (int i = 0; i < 4; i++)
#pragma unroll
        for (int j = 0; j < 4; j++)
          acc[i][j] = __builtin_amdgcn_mfma_f32_16x16x32_bf16(af[i], bfr[j], acc[i][j], 0, 0, 0);
    }
    __syncthreads();
  }

  // fully-unrolled per-wave LDS transpose epilogue (no barriers, acc static)
#pragma unroll
  for (int i = 0; i < 4; i++) {
#pragma unroll
    for (int j = 0; j < 4; j++) {
#pragma unroll
      for (int r = 0; r < 4; r++) tb[wv][kq * 4 + r][fr] = acc[i][j][r];
#pragma unroll
      for (int rr = 0; rr < 4; rr++) {
        const int cloc = kq * 4 + rr;
        const int mg = m0 + wr * 64 + i * 16 + fr;
        const int b = mg >> 10, t = mg & 1023;
        const int c = n0 + wc * 64 + j * 16 + cloc;
        out[((size_t)b * NC + c) * NT + t] =
            tb[wv][fr][cloc] + bo[c] + X[((size_t)b * NC + c) * NT + t];
      }
    }
  }
}

// ---------------------------------------------------------------------------
extern "C" void kernel_launch(void* const* d_in, const int* in_sizes, int n_in,
                              void* d_out, int out_size, void* d_ws, size_t ws_size,
                              hipStream_t stream) {
  const float* X   = (const float*)d_in[0];
  const float* lng = (const float*)d_in[1];
  const float* lnb = (const float*)d_in[2];
  const float* Wq  = (const float*)d_in[3];
  const float* bq  = (const float*)d_in[4];
  const float* Wk  = (const float*)d_in[5];
  const float* bk  = (const float*)d_in[6];
  const float* Wv  = (const float*)d_in[7];
  const float* bv  = (const float*)d_in[8];
  const float* Wo  = (const float*)d_in[9];
  const float* bo  = (const float*)d_in[10];
  float* out = (float*)d_out;

  __bf16* wsb   = (__bf16*)d_ws;
  __bf16* Wtqkv = wsb;                 // [1536][512]
  __bf16* Wot   = wsb + 786432;        // [512][512]
  __bf16* xn    = wsb + 1048576;       // [16384][512]
  __bf16* qbuf  = wsb + 9437184;       // [B][H][T][D] (pre-scaled by log2e/8)
  __bf16* kbuf  = wsb + 17825792;      // [B][H][T][D]
  __bf16* vtbuf = wsb + 26214400;      // [B][H][D][T]
  __bf16* hbuf  = wsb + 34603008;      // [16384][512]

  wt_convert4<<<dim3(256, 4), 256, 0, stream>>>(
      Wq, Wk, Wv, Wo, Wtqkv, Wtqkv + 262144, Wtqkv + 524288, Wot);
  ln_kernel<<<NB * (NT / 16), 256, 0, stream>>>(X, lng, lnb, xn);
  gemm_qkv<<<128 * 12, 256, 0, stream>>>(xn, Wtqkv, bq, bk, bv, qbuf, kbuf, vtbuf);
  attn_kernel<<<1024, 128, 0, stream>>>(qbuf, kbuf, vtbuf, hbuf);
  gemm_out<<<128 * 4, 256, 0, stream>>>(hbuf, Wot, bo, X, out);
}

// Round 24
// 127.211 us; speedup vs baseline: 1.2170x; 1.0351x over previous
//
#include <hip/hip_runtime.h>
#include <hip/hip_bf16.h>
#include <cstdint>
#include <cstddef>

typedef __attribute__((ext_vector_type(8))) __bf16 bf16x8;
typedef __attribute__((ext_vector_type(4))) float f32x4;
typedef __attribute__((ext_vector_type(16))) float f32x16;
typedef __attribute__((ext_vector_type(4))) unsigned short u16x4;
typedef __attribute__((ext_vector_type(4))) unsigned int u32x4;
typedef unsigned int u32;

#define NB 16
#define NC 512
#define NT 1024
#define NH 8
#define ND 64
#define NE 512

// async global->LDS, 16B per lane; lds ptr must be wave-uniform base
__device__ __forceinline__ void gld16(void* lds, const void* g) {
  __builtin_amdgcn_global_load_lds(
      (const __attribute__((address_space(1))) u32*)g,
      (__attribute__((address_space(3))) u32*)lds, 16, 0, 0);
}

__device__ __forceinline__ unsigned short f2bf(float f) {
  __bf16 h = (__bf16)f;
  return __builtin_bit_cast(unsigned short, h);
}

// hardware exp2 (v_exp_f32 computes 2^x)
__device__ __forceinline__ float ex2(float x) {
  float r; asm("v_exp_f32 %0, %1" : "=v"(r) : "v"(x)); return r;
}

// vdst.hi32 <-> vsrc.lo32 lane swap; both values updated (distinct regs!)
__device__ __forceinline__ void pl32swap(u32& a, u32& b) {
  asm("v_permlane32_swap_b32 %0, %1" : "+v"(a), "+v"(b));
}

// ---- fused front kernel: blocks [0,1024) = LayerNorm; [1024,2048) = wt cvt
__global__ __launch_bounds__(256) void ln_wt_fused(
    const float* __restrict__ X, const float* __restrict__ gam,
    const float* __restrict__ bet, __bf16* __restrict__ xn,
    const float* __restrict__ Wq, const float* __restrict__ Wk,
    const float* __restrict__ Wv, const float* __restrict__ Wo,
    __bf16* __restrict__ Wtq, __bf16* __restrict__ Wtk,
    __bf16* __restrict__ Wtv, __bf16* __restrict__ Wto)
{
  __shared__ __align__(16) char smem[16 * 513 * 4 + 128];
  const int tid = threadIdx.x;
  if (blockIdx.x < 1024) {
    // ---------------- LayerNorm over C after (B,C,T)->(B,T,C) transpose ----
    float (*tile)[513] = (float(*)[513])smem;
    float* mu_s = (float*)(smem + 16 * 513 * 4);
    float* rs_s = mu_s + 16;
    const int b  = blockIdx.x >> 6;
    const int t0 = (blockIdx.x & 63) << 4;
    const int tl = tid & 15, c0 = tid >> 4;
    const float* Xb = X + (size_t)b * NC * NT + t0;
    for (int c = c0; c < NC; c += 16)
      tile[tl][c] = Xb[(size_t)c * NT + tl];
    __syncthreads();
    const int row = tid >> 4, sub = tid & 15;
    float s = 0.f, s2 = 0.f;
    for (int c = sub; c < NC; c += 16) { const float v = tile[row][c]; s += v; s2 += v * v; }
    s += __shfl_xor(s, 1);  s2 += __shfl_xor(s2, 1);
    s += __shfl_xor(s, 2);  s2 += __shfl_xor(s2, 2);
    s += __shfl_xor(s, 4);  s2 += __shfl_xor(s2, 4);
    s += __shfl_xor(s, 8);  s2 += __shfl_xor(s2, 8);
    const float mu   = s * (1.f / NC);
    const float var  = s2 * (1.f / NC) - mu * mu;
    const float rstd = rsqrtf(var + 1e-6f);
    if (sub == 0) { mu_s[row] = mu; rs_s[row] = rstd; }
    __syncthreads();
    __bf16* xo = xn + ((size_t)b * NT + t0) * NC;
    for (int i = tid; i < 16 * NC; i += 256) {
      const int r = i >> 9, c = i & (NC - 1);
      xo[(size_t)r * NC + c] = (__bf16)((tile[r][c] - mu_s[r]) * rs_s[r] * gam[c] + bet[c]);
    }
  } else {
    // ---------------- weight transpose+convert (coalesced both sides) ------
    float (*tile)[33] = (float(*)[33])smem;
    const int wb = blockIdx.x - 1024;
    const int w = wb >> 8, inner = wb & 255;
    const float* W = (w == 0) ? Wq : (w == 1) ? Wk : (w == 2) ? Wv : Wo;
    __bf16*     Wt = (w == 0) ? Wtq : (w == 1) ? Wtk : (w == 2) ? Wtv : Wto;
    const int bx = inner & 15, by = inner >> 4;
    const int r0 = by * 32, c0 = bx * 32;
    const int tx = tid & 31, ty = tid >> 5;
#pragma unroll
    for (int i = 0; i < 4; i++)
      tile[ty + i * 8][tx] = W[(size_t)(r0 + ty + i * 8) * 512 + c0 + tx];
    __syncthreads();
#pragma unroll
    for (int i = 0; i < 4; i++) {
      const int cc = ty + i * 8;
      Wt[(size_t)(c0 + cc) * 512 + r0 + tx] = (__bf16)tile[tx][cc];
    }
  }
}

// ---------------- QKV GEMM: xn[16384][512] @ Wt[1536][512]^T ---------------
// BK=64, XOR-swizzled LDS (conflict-free b128 reads), 8 K-iterations
__global__ __launch_bounds__(256) void gemm_qkv(
    const __bf16* __restrict__ A, const __bf16* __restrict__ Wt,
    const float* __restrict__ bq, const float* __restrict__ bk, const float* __restrict__ bv,
    __bf16* __restrict__ qb, __bf16* __restrict__ kb, __bf16* __restrict__ vtb)
{
  __shared__ __align__(16) __bf16 lA[128 * 64];   // [128 m][64 k], swizzled
  __shared__ __align__(16) __bf16 lB[128 * 64];   // [128 n][64 k], swizzled
  __shared__ float tb[4][16][17];
  const int tid = threadIdx.x;
  const int wv = tid >> 6, lane = tid & 63;
  const int bid = blockIdx.x;
  const int mchunk = bid / 192, rem = bid % 192;
  const int xcd = rem & 7, loc = rem >> 3;           // loc 0..23
  const int mt = mchunk * 16 + xcd * 2 + (loc / 12);
  const int nt = loc % 12;
  const int m0 = mt << 7, n0 = nt << 7;
  const int fr = lane & 15, kq = lane >> 4;
  const int wr = wv >> 1, wc = wv & 1;
  const int swz = (fr & 7) << 4;

  const int so  = wv * 1024 + lane * 16;
  const int srr = so >> 7;
  const int scb = (so & 127) ^ ((srr & 7) << 4);
  const char* Asrc = (const char*)A  + (size_t)(m0 + srr) * 1024 + scb;
  const char* Bsrc = (const char*)Wt + (size_t)(n0 + srr) * 1024 + scb;

  f32x4 acc[4][4] = {};
  for (int k0 = 0; k0 < 8; k0++) {
#pragma unroll
    for (int is = 0; is < 4; is++) {
      gld16((char*)lA + is * 4096 + wv * 1024, Asrc + k0 * 128 + (size_t)is * 32768);
      gld16((char*)lB + is * 4096 + wv * 1024, Bsrc + k0 * 128 + (size_t)is * 32768);
    }
    __syncthreads();
#pragma unroll
    for (int kk = 0; kk < 2; kk++) {
      bf16x8 af[4], bfr[4];
#pragma unroll
      for (int i = 0; i < 4; i++) {
        af[i]  = *(const bf16x8*)((const char*)lA +
                   (wr * 64 + i * 16 + fr) * 128 + ((kk * 64 + kq * 16) ^ swz));
        bfr[i] = *(const bf16x8*)((const char*)lB +
                   (wc * 64 + i * 16 + fr) * 128 + ((kk * 64 + kq * 16) ^ swz));
      }
#pragma unroll
      for (int i = 0; i < 4; i++)
#pragma unroll
        for (int j = 0; j < 4; j++)
          acc[i][j] = __builtin_amdgcn_mfma_f32_16x16x32_bf16(af[i], bfr[j], acc[i][j], 0, 0, 0);
    }
    __syncthreads();
  }

  const int wsel = n0 >> 9;  // 0=q 1=k 2=v (uniform per block)
  const float* bias = (wsel == 0) ? bq : (wsel == 1) ? bk : bv;
  const float qsc = (wsel == 0) ? 0.18033688011112042f : 1.0f;  // (1/8)*log2(e)
  if (wsel < 2) {
#pragma unroll
    for (int i = 0; i < 4; i++) {
#pragma unroll
      for (int j = 0; j < 4; j++) {
        const int ng = (n0 & 511) + wc * 64 + j * 16 + fr;
        const int hh = ng >> 6, dd = ng & 63;
        const float bb = bias[ng];
#pragma unroll
        for (int r = 0; r < 4; r++) {
          const int mg = m0 + wr * 64 + i * 16 + kq * 4 + r;
          const int b = mg >> 10, t = mg & 1023;
          const __bf16 h16 = (__bf16)((acc[i][j][r] + bb) * qsc);
          if (wsel == 0) qb[(((size_t)b * NH + hh) * NT + t) * ND + dd] = h16;
          else           kb[(((size_t)b * NH + hh) * NT + t) * ND + dd] = h16;
        }
      }
    }
  } else {
    // V: per-wave LDS transpose (tb[wv] is wave-private -> no barriers)
#pragma unroll
    for (int i = 0; i < 4; i++) {
#pragma unroll
      for (int j = 0; j < 4; j++) {
#pragma unroll
        for (int r = 0; r < 4; r++) tb[wv][kq * 4 + r][fr] = acc[i][j][r];
#pragma unroll
        for (int rr = 0; rr < 4; rr++) {
          const int cloc = kq * 4 + rr;
          const int ng = (n0 & 511) + wc * 64 + j * 16 + cloc;
          const int hh = ng >> 6, dd = ng & 63;
          const int mg = m0 + wr * 64 + i * 16 + fr;
          const int b = mg >> 10, t = mg & 1023;
          vtb[(((size_t)b * NH + hh) * ND + dd) * NT + t] =
              (__bf16)(tb[wv][fr][cloc] + bias[ng]);
        }
      }
    }
  }
}

// ---------------- flash attention: 32x32 MFMA, pure-exp2 softmax ------------
// r19 known-best: counted-vmcnt pipeline, both-softmaxes-first scheduling,
// deferred l-reduction, hoisted stage addressing
__global__ __launch_bounds__(128, 2) void attn_kernel(
    const __bf16* __restrict__ qb, const __bf16* __restrict__ kb,
    const __bf16* __restrict__ vtb, __bf16* __restrict__ hb)
{
  __shared__ __align__(16) __bf16 lK[2][4096];   // [64 k][64 d], swizzled
  __shared__ __align__(16) __bf16 lV[2][4096];   // [64 d][64 t], swizzled
  const int tid = threadIdx.x, wv = tid >> 6, lane = tid & 63;
  const int l31 = lane & 31, hi = lane >> 5;
  const int swz = (l31 & 7) << 4;
  const int bid = blockIdx.x;
  const int xcd = bid & 7, idx = bid >> 3;       // idx 0..127
  const int hbp = xcd * 16 + (idx >> 3);         // 0..127 = b*8+h
  const int chunk = idx & 7;
  const int b = hbp >> 3, hh = hbp & 7;
  const int q0 = chunk * 128 + wv * 64;          // wave's 64 q-rows

  const __bf16* Q = qb + ((size_t)b * NH + hh) * NT * ND;
  const char* Kc = (const char*)(kb  + ((size_t)b * NH + hh) * NT * ND);  // row 128B
  const char* Vc = (const char*)(vtb + ((size_t)b * NH + hh) * ND * NT);  // row 2048B

  const int so  = wv * 1024 + lane * 16;
  const int srr = so >> 7;
  const int scb = (so & 127) ^ ((srr & 7) << 4);
  const char* Ksrc0 = Kc + (size_t)srr * 128 + scb;
  const char* Vsrc0 = Vc + (size_t)srr * 2048 + scb;

  bf16x8 qf[2][4];
#pragma unroll
  for (int qs = 0; qs < 2; qs++)
#pragma unroll
    for (int ds = 0; ds < 4; ds++)
      qf[qs][ds] = *(const bf16x8*)&Q[(size_t)(q0 + qs * 32 + l31) * ND + ds * 16 + hi * 8];

  float l_run[2] = {0.f, 0.f};   // per-lane HALF sums; cross-half reduce at end
  f32x16 O[2][2] = {};
  const f32x16 zz = {};

  auto stage = [&](int nb, int kt64) {
#pragma unroll
    for (int is = 0; is < 4; is++) {
      gld16((char*)&lK[nb][0] + is * 2048 + wv * 1024,
            Ksrc0 + (size_t)kt64 * 128 + is * 2048);
      gld16((char*)&lV[nb][0] + is * 2048 + wv * 1024,
            Vsrc0 + (size_t)kt64 * 2 + is * 32768);
    }
  };

  stage(0, 0);
  stage(1, 64);

#pragma unroll 1
  for (int ti = 0; ti < 16; ti++) {
    const int cur = ti & 1;
    if (ti < 15) asm volatile("s_waitcnt vmcnt(8)" ::: "memory");
    else         asm volatile("s_waitcnt vmcnt(0)" ::: "memory");
    __builtin_amdgcn_s_barrier();
    __builtin_amdgcn_sched_barrier(0);
    const char* Kb = (const char*)&lK[cur][0];
    const char* Vb = (const char*)&lV[cur][0];

    // ---- QK^T: st[qs][ksub] = S^T[k = 32ksub+crow][q = l31] (log2 domain)
    f32x16 st[2][2];
    __builtin_amdgcn_s_setprio(1);
#pragma unroll
    for (int ks = 0; ks < 2; ks++) {
#pragma unroll
      for (int ds = 0; ds < 4; ds++) {
        const int row = ks * 32 + l31;
        const bf16x8 ka = *(const bf16x8*)
            (Kb + row * 128 + ((ds * 32 + hi * 16) ^ swz));
        if (ds == 0) {
          st[0][ks] = __builtin_amdgcn_mfma_f32_32x32x16_bf16(ka, qf[0][0], zz, 0, 0, 0);
          st[1][ks] = __builtin_amdgcn_mfma_f32_32x32x16_bf16(ka, qf[1][0], zz, 0, 0, 0);
        } else {
          st[0][ks] = __builtin_amdgcn_mfma_f32_32x32x16_bf16(ka, qf[0][ds], st[0][ks], 0, 0, 0);
          st[1][ks] = __builtin_amdgcn_mfma_f32_32x32x16_bf16(ka, qf[1][ds], st[1][ks], 0, 0, 0);
        }
      }
    }
    __builtin_amdgcn_s_setprio(0);

    // ---- both softmaxes first (pure exp2; base cancels in l-div)
    u32 pk[2][2][4][2];
#pragma unroll
    for (int qs = 0; qs < 2; qs++) {
      float rs = 0.f;
#pragma unroll
      for (int ks = 0; ks < 2; ks++)
#pragma unroll
        for (int g = 0; g < 4; g++) {
          const float p0 = ex2(st[qs][ks][4 * g + 0]);
          const float p1 = ex2(st[qs][ks][4 * g + 1]);
          const float p2 = ex2(st[qs][ks][4 * g + 2]);
          const float p3 = ex2(st[qs][ks][4 * g + 3]);
          rs += (p0 + p1) + (p2 + p3);
          asm("v_cvt_pk_bf16_f32 %0, %1, %2" : "=v"(pk[qs][ks][g][0]) : "v"(p0), "v"(p1));
          asm("v_cvt_pk_bf16_f32 %0, %1, %2" : "=v"(pk[qs][ks][g][1]) : "v"(p2), "v"(p3));
        }
      l_run[qs] += rs;
    }

    // ---- both PV clusters: 4 independent accumulation chains (qs x dsub)
    __builtin_amdgcn_s_setprio(1);
#pragma unroll
    for (int qs = 0; qs < 2; qs++) {
#pragma unroll
      for (int s = 0; s < 4; s++) {
        const int t = s >> 1, m = s & 1;
        u32 a0 = pk[qs][t][2 * m][0], b0 = pk[qs][t][2 * m + 1][0];
        u32 a1 = pk[qs][t][2 * m][1], b1 = pk[qs][t][2 * m + 1][1];
        pl32swap(a0, b0);
        pl32swap(a1, b1);
        u32x4 w;
        w[0] = a0; w[1] = a1; w[2] = b0; w[3] = b1;
        const bf16x8 pfrag = __builtin_bit_cast(bf16x8, w);
#pragma unroll
        for (int dsub = 0; dsub < 2; dsub++) {
          const int row = dsub * 32 + l31;
          const bf16x8 vf = *(const bf16x8*)
              (Vb + row * 128 + ((s * 32 + hi * 16) ^ swz));
          O[qs][dsub] = __builtin_amdgcn_mfma_f32_32x32x16_bf16(vf, pfrag, O[qs][dsub], 0, 0, 0);
        }
      }
    }
    __builtin_amdgcn_s_setprio(0);

    __builtin_amdgcn_s_barrier();
    __builtin_amdgcn_sched_barrier(0);
    if (ti + 2 < 16) stage(cur, (ti + 2) * 64);
  }

#pragma unroll
  for (int qs = 0; qs < 2; qs++) {
    const float lt = l_run[qs] + __shfl_xor(l_run[qs], 32);
    const float linv = 1.f / lt;
    const int t = q0 + qs * 32 + l31;
    __bf16* hrow = hb + ((size_t)b * NT + t) * NE + hh * ND;
#pragma unroll
    for (int dsub = 0; dsub < 2; dsub++)
#pragma unroll
      for (int g = 0; g < 4; g++) {
        u16x4 ov;
#pragma unroll
        for (int rr = 0; rr < 4; rr++) ov[rr] = f2bf(O[qs][dsub][4 * g + rr] * linv);
        *(u16x4*)&hrow[dsub * 32 + g * 8 + hi * 4] = ov;
      }
  }
}

// ---------------- out proj + bias + residual + transpose store -------------
// BK=64, XOR-swizzled LDS, 8 K-iterations; XCD-swizzled grid 512
__global__ __launch_bounds__(256) void gemm_out(
    const __bf16* __restrict__ A, const __bf16* __restrict__ Wt,
    const float* __restrict__ bo, const float* __restrict__ X,
    float* __restrict__ out)
{
  __shared__ __align__(16) __bf16 lA[128 * 64];
  __shared__ __align__(16) __bf16 lB[128 * 64];
  __shared__ float tb[4][16][17];
  const int tid = threadIdx.x, wv = tid >> 6, lane = tid & 63;
  const int bid = blockIdx.x;
  const int mt = ((bid >> 5) << 3) + (bid & 7);
  const int nt = (bid & 31) >> 3;
  const int m0 = mt << 7, n0 = nt << 7;
  const int fr = lane & 15, kq = lane >> 4;
  const int wr = wv >> 1, wc = wv & 1;
  const int swz = (fr & 7) << 4;

  const int so  = wv * 1024 + lane * 16;
  const int srr = so >> 7;
  const int scb = (so & 127) ^ ((srr & 7) << 4);
  const char* Asrc = (const char*)A  + (size_t)(m0 + srr) * 1024 + scb;
  const char* Bsrc = (const char*)Wt + (size_t)(n0 + srr) * 1024 + scb;

  f32x4 acc[4][4] = {};
  for (int k0 = 0; k0 < 8; k0++) {
#pragma unroll
    for (int is = 0; is < 4; is++) {
      gld16((char*)lA + is * 4096 + wv * 1024, Asrc + k0 * 128 + (size_t)is * 32768);
      gld16((char*)lB + is * 4096 + wv * 1024, Bsrc + k0 * 128 + (size_t)is * 32768);
    }
    __syncthreads();
#pragma unroll
    for (int kk = 0; kk < 2; kk++) {
      bf16x8 af[4], bfr[4];
#pragma unroll
      for (int i = 0; i < 4; i++) {
        af[i]  = *(const bf16x8*)((const char*)lA +
                   (wr * 64 + i * 16 + fr) * 128 + ((kk * 64 + kq * 16) ^ swz));
        bfr[i] = *(const bf16x8*)((const char*)lB +
                   (wc * 64 + i * 16 + fr) * 128 + ((kk * 64 + kq * 16) ^ swz));
      }
#pragma unroll
      for (int i = 0; i < 4; i++)
#pragma unroll
        for (int j = 0; j < 4; j++)
          acc[i][j] = __builtin_amdgcn_mfma_f32_16x16x32_bf16(af[i], bfr[j], acc[i][j], 0, 0, 0);
    }
    __syncthreads();
  }

  // fully-unrolled per-wave LDS transpose epilogue (no barriers, acc static)
#pragma unroll
  for (int i = 0; i < 4; i++) {
#pragma unroll
    for (int j = 0; j < 4; j++) {
#pragma unroll
      for (int r = 0; r < 4; r++) tb[wv][kq * 4 + r][fr] = acc[i][j][r];
#pragma unroll
      for (int rr = 0; rr < 4; rr++) {
        const int cloc = kq * 4 + rr;
        const int mg = m0 + wr * 64 + i * 16 + fr;
        const int b = mg >> 10, t = mg & 1023;
        const int c = n0 + wc * 64 + j * 16 + cloc;
        out[((size_t)b * NC + c) * NT + t] =
            tb[wv][fr][cloc] + bo[c] + X[((size_t)b * NC + c) * NT + t];
      }
    }
  }
}

// ---------------------------------------------------------------------------
extern "C" void kernel_launch(void* const* d_in, const int* in_sizes, int n_in,
                              void* d_out, int out_size, void* d_ws, size_t ws_size,
                              hipStream_t stream) {
  const float* X   = (const float*)d_in[0];
  const float* lng = (const float*)d_in[1];
  const float* lnb = (const float*)d_in[2];
  const float* Wq  = (const float*)d_in[3];
  const float* bq  = (const float*)d_in[4];
  const float* Wk  = (const float*)d_in[5];
  const float* bk  = (const float*)d_in[6];
  const float* Wv  = (const float*)d_in[7];
  const float* bv  = (const float*)d_in[8];
  const float* Wo  = (const float*)d_in[9];
  const float* bo  = (const float*)d_in[10];
  float* out = (float*)d_out;

  __bf16* wsb   = (__bf16*)d_ws;
  __bf16* Wtqkv = wsb;                 // [1536][512]
  __bf16* Wot   = wsb + 786432;        // [512][512]
  __bf16* xn    = wsb + 1048576;       // [16384][512]
  __bf16* qbuf  = wsb + 9437184;       // [B][H][T][D] (pre-scaled by log2e/8)
  __bf16* kbuf  = wsb + 17825792;      // [B][H][T][D]
  __bf16* vtbuf = wsb + 26214400;      // [B][H][D][T]
  __bf16* hbuf  = wsb + 34603008;      // [16384][512]

  ln_wt_fused<<<2048, 256, 0, stream>>>(
      X, lng, lnb, xn,
      Wq, Wk, Wv, Wo, Wtqkv, Wtqkv + 262144, Wtqkv + 524288, Wot);
  gemm_qkv<<<128 * 12, 256, 0, stream>>>(xn, Wtqkv, bq, bk, bv, qbuf, kbuf, vtbuf);
  attn_kernel<<<1024, 128, 0, stream>>>(qbuf, kbuf, vtbuf, hbuf);
  gemm_out<<<128 * 4, 256, 0, stream>>>(hbuf, Wot, bo, X, out);
}